// Round 5
// baseline (493.925 us; speedup 1.0000x reference)
//
#include <hip/hip_runtime.h>

typedef unsigned short u16;
typedef __bf16 bf16x8 __attribute__((ext_vector_type(8)));
typedef float f32x4 __attribute__((ext_vector_type(4)));

constexpr int Bq  = 4;
constexpr int Sq  = 2048;
constexpr int Hq  = 1024;
constexpr int NHq = 16;
constexpr int HDq = 64;
constexpr int CCH = 16;    // chunks
constexpr int LCH = 128;   // chunk length

// workspace layout (bytes), total 212,860,928
constexpr size_t OFF_WB = 0;             // W bf16: 5*1M*2 = 10,485,760
constexpr size_t OFF_XB = 10485760;      // 16,777,216: x-bf16 -> Qc (scan) -> y-bf16 (epilogue)
constexpr size_t OFF_Q  = 27262976;      // q fp32: 33,554,432
constexpr size_t OFF_K  = 60817408;
constexpr size_t OFF_V  = 94371840;
constexpr size_t OFF_G  = 127926272;
constexpr size_t OFF_AL = 161480704;     // alpha: 524,288
constexpr size_t OFF_BE = 162004992;
constexpr size_t OFF_P  = 162529280;     // Wab bf16 (256 KB) during GEMM -> chunk P (16 MB) during scan
constexpr size_t OFF_O  = 179306496;     // of fp32: 33,554,432 (end 212,860,928)

__device__ __forceinline__ u16 f2bf(float f) {
  unsigned u = __float_as_uint(f);
  u += 0x7fffu + ((u >> 16) & 1u);
  return (u16)(u >> 16);
}
__device__ __forceinline__ float sigmoidf_(float x) { return 1.f / (1.f + __expf(-x)); }

__device__ __forceinline__ void async16(const u16* g, u16* l) {
  __builtin_amdgcn_global_load_lds((const __attribute__((address_space(1))) void*)(const void*)g,
                                   (__attribute__((address_space(3))) void*)(void*)l, 16, 0, 0);
}

// ---------------- converts ----------------
__global__ __launch_bounds__(256) void cvt_x_kernel(const float* __restrict__ in, u16* __restrict__ outp) {
  const size_t i = ((size_t)blockIdx.x * 256 + threadIdx.x) * 4;
  float4 f = *(const float4*)(in + i);
  ushort4 u; u.x = f2bf(f.x); u.y = f2bf(f.y); u.z = f2bf(f.z); u.w = f2bf(f.w);
  *(ushort4*)(outp + i) = u;
}

__global__ __launch_bounds__(256) void cvt_w_kernel(const float* __restrict__ w0, const float* __restrict__ w1,
    const float* __restrict__ w2, const float* __restrict__ w3, const float* __restrict__ w4,
    u16* __restrict__ outp) {
  const int z = blockIdx.z;
  const float* src = (z == 0) ? w0 : (z == 1) ? w1 : (z == 2) ? w2 : (z == 3) ? w3 : w4;
  const size_t i = ((size_t)blockIdx.x * 256 + threadIdx.x) * 4;
  float4 f = *(const float4*)(src + i);
  ushort4 u; u.x = f2bf(f.x); u.y = f2bf(f.y); u.z = f2bf(f.z); u.w = f2bf(f.w);
  *(ushort4*)(outp + (size_t)z * (1024 * 1024) + i) = u;
}

// Wab: 128x1024 bf16; rows 0..15 = Wa, 16..31 = Wb, rest zero
__global__ __launch_bounds__(256) void cvt_ab_kernel(const float* __restrict__ Wa, const float* __restrict__ Wb,
    u16* __restrict__ outp) {
  const size_t i = ((size_t)blockIdx.x * 256 + threadIdx.x) * 4;
  const int row = (int)(i >> 10);
  ushort4 u;
  if (row < 32) {
    const float* src = (row < 16) ? (Wa + i) : (Wb + i - 16 * 1024);
    float4 f = *(const float4*)src;
    u.x = f2bf(f.x); u.y = f2bf(f.y); u.z = f2bf(f.z); u.w = f2bf(f.w);
  } else {
    u.x = u.y = u.z = u.w = 0;
  }
  *(ushort4*)(outp + i) = u;
}

// ---------------- bf16 MFMA GEMM (m97 structure) with fused epilogues ----------------
// mode 0: plain store to Cq.
// mode 1: z=0 q(l2norm), z=1 k(l2norm), z=2 v(silu), z=3 g(plain), z=4 alpha/beta(sigmoid+bias, y==0 only)
__global__ __launch_bounds__(256) void gemm_bt(const u16* __restrict__ A, const u16* __restrict__ Wall,
    const u16* __restrict__ Wab,
    float* __restrict__ Cq, float* __restrict__ Ck, float* __restrict__ Cv, float* __restrict__ Cg,
    float* __restrict__ al, float* __restrict__ be,
    const float* __restrict__ ba, const float* __restrict__ bb, int mode) {
  constexpr int GK = 1024, GN = 1024;
  const int z = blockIdx.z;
  if (mode == 1 && z == 4 && blockIdx.y > 0) return;
  __shared__ __align__(16) u16 As[128 * 32];
  __shared__ __align__(16) u16 Bs[128 * 32];
  const int tid = threadIdx.x;
  const int w = tid >> 6, lane = tid & 63;
  const int m0 = blockIdx.x * 128, n0 = blockIdx.y * 128;
  const u16* W = (mode == 1 && z == 4) ? Wab : (Wall + (size_t)z * (1024 * 1024));
  const int rrow = lane >> 2;
  const int kc8 = (lane & 3) * 8;
  const u16* gA = A + (size_t)(m0 + w * 32 + rrow) * GK + kc8;
  const u16* gB = W + (size_t)(n0 + w * 32 + rrow) * GK + kc8;
  u16* lA = As + (w * 32) * 32;
  u16* lB = Bs + (w * 32) * 32;
  const int qd = lane >> 4, l15 = lane & 15;
  const int wm = (w >> 1) * 64, wn = (w & 1) * 64;
  f32x4 acc[4][4] = {};
  for (int kt = 0; kt < GK; kt += 32) {
    async16(gA,           lA);
    async16(gA + 16 * GK, lA + 16 * 32);
    async16(gB,           lB);
    async16(gB + 16 * GK, lB + 16 * 32);
    gA += 32; gB += 32;
    __syncthreads();
    bf16x8 af[4], bfr[4];
    #pragma unroll
    for (int i = 0; i < 4; ++i) {
      af[i]  = *(const bf16x8*)(As + (wm + i * 16 + l15) * 32 + qd * 8);
      bfr[i] = *(const bf16x8*)(Bs + (wn + i * 16 + l15) * 32 + qd * 8);
    }
    #pragma unroll
    for (int i = 0; i < 4; ++i)
      #pragma unroll
      for (int j = 0; j < 4; ++j)
        acc[i][j] = __builtin_amdgcn_mfma_f32_16x16x32_bf16(af[i], bfr[j], acc[i][j], 0, 0, 0);
    __syncthreads();
  }
  // ---- epilogues ---- C/D layout: col = l15, row = qd*4 + reg
  if (mode == 1 && z == 4) {
    if (wn == 0) {
      const float bav = ba[l15], bbv = bb[l15];
      #pragma unroll
      for (int i = 0; i < 4; ++i) {
        const int row = m0 + wm + i * 16 + qd * 4;
        #pragma unroll
        for (int r = 0; r < 4; ++r) {
          al[(size_t)(row + r) * 16 + l15] = sigmoidf_(acc[i][0][r] + bav);
          be[(size_t)(row + r) * 16 + l15] = sigmoidf_(acc[i][1][r] + bbv);
        }
      }
    }
    return;
  }
  if (mode == 1 && (z == 0 || z == 1)) {
    #pragma unroll
    for (int i = 0; i < 4; ++i)
      #pragma unroll
      for (int r = 0; r < 4; ++r) {
        float ss = acc[i][0][r] * acc[i][0][r] + acc[i][1][r] * acc[i][1][r]
                 + acc[i][2][r] * acc[i][2][r] + acc[i][3][r] * acc[i][3][r];
        ss += __shfl_xor(ss, 1); ss += __shfl_xor(ss, 2);
        ss += __shfl_xor(ss, 4); ss += __shfl_xor(ss, 8);
        const float rn = 1.f / fmaxf(sqrtf(ss), 1e-12f);
        acc[i][0][r] *= rn; acc[i][1][r] *= rn; acc[i][2][r] *= rn; acc[i][3][r] *= rn;
      }
  } else if (mode == 1 && z == 2) {
    #pragma unroll
    for (int i = 0; i < 4; ++i)
      #pragma unroll
      for (int j = 0; j < 4; ++j)
        #pragma unroll
        for (int r = 0; r < 4; ++r)
          acc[i][j][r] = acc[i][j][r] * sigmoidf_(acc[i][j][r]);
  }
  float* C = (mode == 0) ? Cq : ((z == 0) ? Cq : (z == 1) ? Ck : (z == 2) ? Cv : Cg);
  #pragma unroll
  for (int i = 0; i < 4; ++i) {
    const int row = m0 + wm + i * 16 + qd * 4;
    #pragma unroll
    for (int j = 0; j < 4; ++j) {
      const int col = n0 + wn + j * 16 + l15;
      #pragma unroll
      for (int r = 0; r < 4; ++r)
        C[(size_t)(row + r) * GN + col] = acc[i][j][r];
    }
  }
}

// ================= chunked scan, row-split: wave = (b,h,chunk,half), 32 rows x 64 cols =================
// lane: rg = lane>>3 (row group of 4), cg = lane&7 (col group of 8). r0 = half*32+rg*4, c8 = cg*8.

struct S1h { float4 kc0, kc1, kr, vr; float a, bt; };
struct S2h { float4 kc0, kc1, qc0, qc1, kr, vr; float a, bt; };

__device__ __forceinline__ void load_s1h(const float* __restrict__ k, const float* __restrict__ v,
    const float* __restrict__ al, const float* __restrict__ be,
    size_t base, size_t ab, int c8, int r0, S1h& s) {
  s.kc0 = *(const float4*)(k + base + c8);  s.kc1 = *(const float4*)(k + base + c8 + 4);
  s.kr  = *(const float4*)(k + base + r0);
  s.vr  = *(const float4*)(v + base + r0);
  s.a = al[ab]; s.bt = be[ab];
}

__device__ __forceinline__ void load_s2h(const float* __restrict__ q, const float* __restrict__ k,
    const float* __restrict__ v, const float* __restrict__ al, const float* __restrict__ be,
    size_t base, size_t ab, int c8, int r0, S2h& s) {
  s.kc0 = *(const float4*)(k + base + c8);  s.kc1 = *(const float4*)(k + base + c8 + 4);
  s.qc0 = *(const float4*)(q + base + c8);  s.qc1 = *(const float4*)(q + base + c8 + 4);
  s.kr  = *(const float4*)(k + base + r0);
  s.vr  = *(const float4*)(v + base + r0);
  s.a = al[ab]; s.bt = be[ab];
}

// pass 1: compose affine maps over the chunk (this wave's 32x64 sub-state)
__global__ __launch_bounds__(256, 2) void scan_p1(const float* __restrict__ k, const float* __restrict__ v,
    const float* __restrict__ al, const float* __restrict__ be,
    float* __restrict__ P, float* __restrict__ Q) {
  const int w = threadIdx.x >> 6, lane = threadIdx.x & 63;
  const int gw = blockIdx.x * 4 + w;          // 0..2047
  const int half = gw & 1;
  const int c = (gw >> 1) & 15;
  const int bh = gw >> 5;                     // 0..63
  const int b = bh >> 4, h = bh & 15;
  const int rg = lane >> 3, cg = lane & 7;
  const int r0 = half * 32 + rg * 4, c8 = cg * 8;
  const int t0 = c * LCH;
  const size_t base0 = ((size_t)(b * Sq + t0)) * 1024 + h * 64;
  const size_t ab0   = ((size_t)(b * Sq + t0)) * 16 + h;
  float Pr[32], Qr[32];
  #pragma unroll
  for (int i = 0; i < 32; ++i) { Pr[i] = 1.f; Qr[i] = 0.f; }
  S1h buf[4];
  #pragma unroll
  for (int d = 0; d < 4; ++d)
    load_s1h(k, v, al, be, base0 + (size_t)d * 1024, ab0 + (size_t)d * 16, c8, r0, buf[d]);
  for (int tb = 0; tb < LCH; tb += 4) {
    #pragma unroll
    for (int d = 0; d < 4; ++d) {
      const S1h s = buf[d];
      const int tn = tb + d + 4;   // dead-load past chunk end stays inside ws: benign
      load_s1h(k, v, al, be, base0 + (size_t)tn * 1024, ab0 + (size_t)tn * 16, c8, r0, buf[d]);
      const float kcv[8] = {s.kc0.x, s.kc0.y, s.kc0.z, s.kc0.w, s.kc1.x, s.kc1.y, s.kc1.z, s.kc1.w};
      const float krv[4] = {s.kr.x, s.kr.y, s.kr.z, s.kr.w};
      const float vrv[4] = {s.vr.x, s.vr.y, s.vr.z, s.vr.w};
      const float abt = s.a * s.bt;
      float c1[4], c2[4];
      #pragma unroll
      for (int i = 0; i < 4; ++i) { c1[i] = abt * krv[i]; c2[i] = s.bt * vrv[i]; }
      #pragma unroll
      for (int i = 0; i < 4; ++i)
        #pragma unroll
        for (int j = 0; j < 8; ++j) {
          const int e = i * 8 + j;
          const float A = fmaf(-c1[i], kcv[j], s.a);
          Qr[e] = fmaf(A, Qr[e], c2[i] * kcv[j]);
          Pr[e] *= A;
        }
    }
  }
  const size_t pbase = ((size_t)bh * CCH + c) * 4096 + (size_t)c8;
  #pragma unroll
  for (int i = 0; i < 4; ++i) {
    const size_t pi = pbase + (size_t)(r0 + i) * 64;
    *(float4*)(P + pi) = make_float4(Pr[i*8],   Pr[i*8+1], Pr[i*8+2], Pr[i*8+3]);
    *(float4*)(P + pi + 4) = make_float4(Pr[i*8+4], Pr[i*8+5], Pr[i*8+6], Pr[i*8+7]);
    *(float4*)(Q + pi) = make_float4(Qr[i*8],   Qr[i*8+1], Qr[i*8+2], Qr[i*8+3]);
    *(float4*)(Q + pi + 4) = make_float4(Qr[i*8+4], Qr[i*8+5], Qr[i*8+6], Qr[i*8+7]);
  }
}

// pass 2: sequential combine over chunks; writes chunk-initial state over P
__global__ __launch_bounds__(256) void scan_comb(float* __restrict__ P, const float* __restrict__ Q) {
  const int g = blockIdx.x * 256 + threadIdx.x;  // 0..262143
  const int elem = g & 4095;
  const int bh = g >> 12;
  float s = 0.f;
  for (int c = 0; c < CCH; ++c) {
    const size_t idx = ((size_t)bh * CCH + c) * 4096 + elem;
    const float p = P[idx], qq = Q[idx];
    P[idx] = s;
    s = fmaf(p, s, qq);
  }
}

// pass 3: re-iterate chunk from s_init, emit outputs
__global__ __launch_bounds__(256, 2) void scan_p2(const float* __restrict__ q, const float* __restrict__ k,
    const float* __restrict__ v, const float* __restrict__ al, const float* __restrict__ be,
    const float* __restrict__ Pini, float* __restrict__ o) {
  const int w = threadIdx.x >> 6, lane = threadIdx.x & 63;
  const int gw = blockIdx.x * 4 + w;
  const int half = gw & 1;
  const int c = (gw >> 1) & 15;
  const int bh = gw >> 5;
  const int b = bh >> 4, h = bh & 15;
  const int rg = lane >> 3, cg = lane & 7;
  const int r0 = half * 32 + rg * 4, c8 = cg * 8;
  const int t0 = c * LCH;
  const size_t base0 = ((size_t)(b * Sq + t0)) * 1024 + h * 64;
  const size_t ab0   = ((size_t)(b * Sq + t0)) * 16 + h;
  const size_t pbase = ((size_t)bh * CCH + c) * 4096 + (size_t)c8;
  float st[32];
  #pragma unroll
  for (int i = 0; i < 4; ++i) {
    float4 s0 = *(const float4*)(Pini + pbase + (size_t)(r0 + i) * 64);
    float4 s1 = *(const float4*)(Pini + pbase + (size_t)(r0 + i) * 64 + 4);
    st[i*8]   = s0.x; st[i*8+1] = s0.y; st[i*8+2] = s0.z; st[i*8+3] = s0.w;
    st[i*8+4] = s1.x; st[i*8+5] = s1.y; st[i*8+6] = s1.z; st[i*8+7] = s1.w;
  }
  S2h buf[4];
  #pragma unroll
  for (int d = 0; d < 4; ++d)
    load_s2h(q, k, v, al, be, base0 + (size_t)d * 1024, ab0 + (size_t)d * 16, c8, r0, buf[d]);
  const bool hi4 = (cg & 4), hi2 = (cg & 2);
  const int rowIdx = r0 + (cg >> 1);
  const bool doStore = ((cg & 1) == 0);
  for (int tb = 0; tb < LCH; tb += 4) {
    #pragma unroll
    for (int d = 0; d < 4; ++d) {
      const int t = tb + d;
      const S2h s = buf[d];
      const int tn = t + 4;        // dead-load past chunk end: benign
      load_s2h(q, k, v, al, be, base0 + (size_t)tn * 1024, ab0 + (size_t)tn * 16, c8, r0, buf[d]);
      const float kcv[8] = {s.kc0.x, s.kc0.y, s.kc0.z, s.kc0.w, s.kc1.x, s.kc1.y, s.kc1.z, s.kc1.w};
      const float qcv[8] = {s.qc0.x, s.qc0.y, s.qc0.z, s.qc0.w, s.qc1.x, s.qc1.y, s.qc1.z, s.qc1.w};
      const float krv[4] = {s.kr.x, s.kr.y, s.kr.z, s.kr.w};
      const float vrv[4] = {s.vr.x, s.vr.y, s.vr.z, s.vr.w};
      const float abt = s.a * s.bt;
      float c1[4], c2[4];
      #pragma unroll
      for (int i = 0; i < 4; ++i) { c1[i] = abt * krv[i]; c2[i] = s.bt * vrv[i]; }
      float p[4];
      #pragma unroll
      for (int i = 0; i < 4; ++i) p[i] = 0.f;
      #pragma unroll
      for (int i = 0; i < 4; ++i)
        #pragma unroll
        for (int j = 0; j < 8; ++j) {
          const int e = i * 8 + j;
          const float A = fmaf(-c1[i], kcv[j], s.a);
          st[e] = fmaf(A, st[e], c2[i] * kcv[j]);
          p[i] = fmaf(st[e], qcv[j], p[i]);
        }
      // reduce-scatter over the 8 col-lanes: stage xor4 (rows 0-1 / 2-3), xor2 (row pick), xor1 (final)
      float r2[2];
      #pragma unroll
      for (int i = 0; i < 2; ++i) {
        const float send = hi4 ? p[i] : p[i + 2];
        const float recv = __shfl_xor(send, 4);
        r2[i] = (hi4 ? p[i + 2] : p[i]) + recv;
      }
      float r1;
      {
        const float send = hi2 ? r2[0] : r2[1];
        const float recv = __shfl_xor(send, 2);
        r1 = (hi2 ? r2[1] : r2[0]) + recv;
      }
      const float tot = r1 + __shfl_xor(r1, 1);
      if (doStore) o[base0 + (size_t)t * 1024 + rowIdx] = tot;
    }
  }
}

// ---------------- LayerNorm + silu-gate, write bf16 ----------------
__global__ __launch_bounds__(256) void ln_gate_kernel(const float* __restrict__ o, const float* __restrict__ g,
    const float* __restrict__ ln_g, const float* __restrict__ ln_b, u16* __restrict__ y) {
  const int t = blockIdx.x, tid = threadIdx.x;
  const size_t row = (size_t)t * 1024;
  float4 xv = *(const float4*)(o + row + tid * 4);
  float s  = xv.x + xv.y + xv.z + xv.w;
  float s2 = xv.x * xv.x + xv.y * xv.y + xv.z * xv.z + xv.w * xv.w;
  #pragma unroll
  for (int m = 1; m < 64; m <<= 1) { s += __shfl_xor(s, m); s2 += __shfl_xor(s2, m); }
  __shared__ float red[8];
  const int w = tid >> 6, lane = tid & 63;
  if (lane == 0) { red[w] = s; red[4 + w] = s2; }
  __syncthreads();
  s  = red[0] + red[1] + red[2] + red[3];
  s2 = red[4] + red[5] + red[6] + red[7];
  const float mu = s * (1.f / 1024.f);
  const float var = s2 * (1.f / 1024.f) - mu * mu;
  const float rstd = rsqrtf(var + 1e-5f);
  float4 gv = *(const float4*)(g + row + tid * 4);
  float4 lg = *(const float4*)(ln_g + tid * 4);
  float4 lb = *(const float4*)(ln_b + tid * 4);
  ushort4 u;
  u.x = f2bf(((xv.x - mu) * rstd * lg.x + lb.x) * (gv.x * sigmoidf_(gv.x)));
  u.y = f2bf(((xv.y - mu) * rstd * lg.y + lb.y) * (gv.y * sigmoidf_(gv.y)));
  u.z = f2bf(((xv.z - mu) * rstd * lg.z + lb.z) * (gv.z * sigmoidf_(gv.z)));
  u.w = f2bf(((xv.w - mu) * rstd * lg.w + lb.w) * (gv.w * sigmoidf_(gv.w)));
  *(ushort4*)(y + row + tid * 4) = u;
}

extern "C" void kernel_launch(void* const* d_in, const int* in_sizes, int n_in,
                              void* d_out, int out_size, void* d_ws, size_t ws_size,
                              hipStream_t stream) {
  const float* x    = (const float*)d_in[0];
  const float* Wq   = (const float*)d_in[1];
  const float* Wk   = (const float*)d_in[2];
  const float* Wv   = (const float*)d_in[3];
  const float* Wa   = (const float*)d_in[4];
  const float* ba   = (const float*)d_in[5];
  const float* Wb   = (const float*)d_in[6];
  const float* bb   = (const float*)d_in[7];
  const float* Wg   = (const float*)d_in[8];
  const float* Wo   = (const float*)d_in[9];
  const float* ln_g = (const float*)d_in[10];
  const float* ln_b = (const float*)d_in[11];
  float* out = (float*)d_out;
  char* ws = (char*)d_ws;

  u16*   wb  = (u16*)(ws + OFF_WB);
  u16*   xb  = (u16*)(ws + OFF_XB);   // x-bf16 -> Qc -> y-bf16
  float* qf  = (float*)(ws + OFF_Q);
  float* kf  = (float*)(ws + OFF_K);
  float* vf  = (float*)(ws + OFF_V);
  float* gf  = (float*)(ws + OFF_G);
  float* al  = (float*)(ws + OFF_AL);
  float* be  = (float*)(ws + OFF_BE);
  u16*   wab = (u16*)(ws + OFF_P);    // Wab bf16 during GEMM; region later becomes P
  float* Pb  = (float*)(ws + OFF_P);
  float* Qc  = (float*)(ws + OFF_XB); // reuses dead x-bf16 region
  float* of  = (float*)(ws + OFF_O);
  u16*   yb  = xb;

  cvt_x_kernel<<<8192, 256, 0, stream>>>(x, xb);
  cvt_w_kernel<<<dim3(1024, 1, 5), 256, 0, stream>>>(Wq, Wk, Wv, Wg, Wo, wb);
  cvt_ab_kernel<<<128, 256, 0, stream>>>(Wa, Wb, wab);
  // projections q,k,v,g + alpha/beta, with fused l2norm/silu/sigmoid epilogues
  gemm_bt<<<dim3(64, 8, 5), 256, 0, stream>>>(xb, wb, wab, qf, kf, vf, gf, al, be, ba, bb, 1);
  // chunked scan (row-split: 2048 waves, 2/SIMD, 4-deep prefetch)
  scan_p1<<<512, 256, 0, stream>>>(kf, vf, al, be, Pb, Qc);
  scan_comb<<<1024, 256, 0, stream>>>(Pb, Qc);
  scan_p2<<<512, 256, 0, stream>>>(qf, kf, vf, al, be, Pb, of);
  // epilogue
  ln_gate_kernel<<<8192, 256, 0, stream>>>(of, gf, ln_g, ln_b, yb);
  gemm_bt<<<dim3(64, 8, 1), 256, 0, stream>>>(yb, wb + (size_t)4 * 1024 * 1024, wab,
                                              out, out, out, out, al, be, ba, bb, 0);
}

// Round 6
// 454.565 us; speedup vs baseline: 1.0866x; 1.0866x over previous
//
#include <hip/hip_runtime.h>

typedef unsigned short u16;
typedef __bf16 bf16x8 __attribute__((ext_vector_type(8)));
typedef float f32x4 __attribute__((ext_vector_type(4)));

constexpr int Bq  = 4;
constexpr int Sq  = 2048;
constexpr int Hq  = 1024;
constexpr int NHq = 16;
constexpr int HDq = 64;
constexpr int CCH = 16;    // chunks
constexpr int LCH = 128;   // chunk length

// workspace layout (bytes), total 212,860,928
constexpr size_t OFF_WB = 0;             // W bf16: 5*1M*2 = 10,485,760
constexpr size_t OFF_XB = 10485760;      // 16,777,216: x-bf16 -> Qc (scan) -> y-bf16 (epilogue)
constexpr size_t OFF_Q  = 27262976;      // q fp32: 33,554,432
constexpr size_t OFF_K  = 60817408;
constexpr size_t OFF_V  = 94371840;
constexpr size_t OFF_G  = 127926272;
constexpr size_t OFF_AL = 161480704;     // alpha: 524,288
constexpr size_t OFF_BE = 162004992;
constexpr size_t OFF_P  = 162529280;     // Wab bf16 (256 KB) during GEMM -> chunk P (16 MB) during scan
constexpr size_t OFF_O  = 179306496;     // of fp32: 33,554,432 (end 212,860,928)

__device__ __forceinline__ u16 f2bf(float f) {
  unsigned u = __float_as_uint(f);
  u += 0x7fffu + ((u >> 16) & 1u);
  return (u16)(u >> 16);
}
__device__ __forceinline__ float sigmoidf_(float x) { return 1.f / (1.f + __expf(-x)); }

__device__ __forceinline__ void async16(const void* g, void* l) {
  __builtin_amdgcn_global_load_lds((const __attribute__((address_space(1))) void*)g,
                                   (__attribute__((address_space(3))) void*)l, 16, 0, 0);
}

// ---------------- converts ----------------
__global__ __launch_bounds__(256) void cvt_x_kernel(const float* __restrict__ in, u16* __restrict__ outp) {
  const size_t i = ((size_t)blockIdx.x * 256 + threadIdx.x) * 4;
  float4 f = *(const float4*)(in + i);
  ushort4 u; u.x = f2bf(f.x); u.y = f2bf(f.y); u.z = f2bf(f.z); u.w = f2bf(f.w);
  *(ushort4*)(outp + i) = u;
}

__global__ __launch_bounds__(256) void cvt_w_kernel(const float* __restrict__ w0, const float* __restrict__ w1,
    const float* __restrict__ w2, const float* __restrict__ w3, const float* __restrict__ w4,
    u16* __restrict__ outp) {
  const int z = blockIdx.z;
  const float* src = (z == 0) ? w0 : (z == 1) ? w1 : (z == 2) ? w2 : (z == 3) ? w3 : w4;
  const size_t i = ((size_t)blockIdx.x * 256 + threadIdx.x) * 4;
  float4 f = *(const float4*)(src + i);
  ushort4 u; u.x = f2bf(f.x); u.y = f2bf(f.y); u.z = f2bf(f.z); u.w = f2bf(f.w);
  *(ushort4*)(outp + (size_t)z * (1024 * 1024) + i) = u;
}

// Wab: 128x1024 bf16; rows 0..15 = Wa, 16..31 = Wb, rest zero
__global__ __launch_bounds__(256) void cvt_ab_kernel(const float* __restrict__ Wa, const float* __restrict__ Wb,
    u16* __restrict__ outp) {
  const size_t i = ((size_t)blockIdx.x * 256 + threadIdx.x) * 4;
  const int row = (int)(i >> 10);
  ushort4 u;
  if (row < 32) {
    const float* src = (row < 16) ? (Wa + i) : (Wb + i - 16 * 1024);
    float4 f = *(const float4*)src;
    u.x = f2bf(f.x); u.y = f2bf(f.y); u.z = f2bf(f.z); u.w = f2bf(f.w);
  } else {
    u.x = u.y = u.z = u.w = 0;
  }
  *(ushort4*)(outp + i) = u;
}

// ---------------- bf16 MFMA GEMM (m97 structure) with fused epilogues ----------------
// mode 0: plain store to Cq.
// mode 1: z=0 q(l2norm), z=1 k(l2norm), z=2 v(silu), z=3 g(plain), z=4 alpha/beta(sigmoid+bias, y==0 only)
__global__ __launch_bounds__(256) void gemm_bt(const u16* __restrict__ A, const u16* __restrict__ Wall,
    const u16* __restrict__ Wab,
    float* __restrict__ Cq, float* __restrict__ Ck, float* __restrict__ Cv, float* __restrict__ Cg,
    float* __restrict__ al, float* __restrict__ be,
    const float* __restrict__ ba, const float* __restrict__ bb, int mode) {
  constexpr int GK = 1024, GN = 1024;
  const int z = blockIdx.z;
  if (mode == 1 && z == 4 && blockIdx.y > 0) return;
  __shared__ __align__(16) u16 As[128 * 32];
  __shared__ __align__(16) u16 Bs[128 * 32];
  const int tid = threadIdx.x;
  const int w = tid >> 6, lane = tid & 63;
  const int m0 = blockIdx.x * 128, n0 = blockIdx.y * 128;
  const u16* W = (mode == 1 && z == 4) ? Wab : (Wall + (size_t)z * (1024 * 1024));
  const int rrow = lane >> 2;
  const int kc8 = (lane & 3) * 8;
  const u16* gA = A + (size_t)(m0 + w * 32 + rrow) * GK + kc8;
  const u16* gB = W + (size_t)(n0 + w * 32 + rrow) * GK + kc8;
  u16* lA = As + (w * 32) * 32;
  u16* lB = Bs + (w * 32) * 32;
  const int qd = lane >> 4, l15 = lane & 15;
  const int wm = (w >> 1) * 64, wn = (w & 1) * 64;
  f32x4 acc[4][4] = {};
  for (int kt = 0; kt < GK; kt += 32) {
    async16(gA,           lA);
    async16(gA + 16 * GK, lA + 16 * 32);
    async16(gB,           lB);
    async16(gB + 16 * GK, lB + 16 * 32);
    gA += 32; gB += 32;
    __syncthreads();
    bf16x8 af[4], bfr[4];
    #pragma unroll
    for (int i = 0; i < 4; ++i) {
      af[i]  = *(const bf16x8*)(As + (wm + i * 16 + l15) * 32 + qd * 8);
      bfr[i] = *(const bf16x8*)(Bs + (wn + i * 16 + l15) * 32 + qd * 8);
    }
    #pragma unroll
    for (int i = 0; i < 4; ++i)
      #pragma unroll
      for (int j = 0; j < 4; ++j)
        acc[i][j] = __builtin_amdgcn_mfma_f32_16x16x32_bf16(af[i], bfr[j], acc[i][j], 0, 0, 0);
    __syncthreads();
  }
  // ---- epilogues ---- C/D layout: col = l15, row = qd*4 + reg
  if (mode == 1 && z == 4) {
    if (wn == 0) {
      const float bav = ba[l15], bbv = bb[l15];
      #pragma unroll
      for (int i = 0; i < 4; ++i) {
        const int row = m0 + wm + i * 16 + qd * 4;
        #pragma unroll
        for (int r = 0; r < 4; ++r) {
          al[(size_t)(row + r) * 16 + l15] = sigmoidf_(acc[i][0][r] + bav);
          be[(size_t)(row + r) * 16 + l15] = sigmoidf_(acc[i][1][r] + bbv);
        }
      }
    }
    return;
  }
  if (mode == 1 && (z == 0 || z == 1)) {
    #pragma unroll
    for (int i = 0; i < 4; ++i)
      #pragma unroll
      for (int r = 0; r < 4; ++r) {
        float ss = acc[i][0][r] * acc[i][0][r] + acc[i][1][r] * acc[i][1][r]
                 + acc[i][2][r] * acc[i][2][r] + acc[i][3][r] * acc[i][3][r];
        ss += __shfl_xor(ss, 1); ss += __shfl_xor(ss, 2);
        ss += __shfl_xor(ss, 4); ss += __shfl_xor(ss, 8);
        const float rn = 1.f / fmaxf(sqrtf(ss), 1e-12f);
        acc[i][0][r] *= rn; acc[i][1][r] *= rn; acc[i][2][r] *= rn; acc[i][3][r] *= rn;
      }
  } else if (mode == 1 && z == 2) {
    #pragma unroll
    for (int i = 0; i < 4; ++i)
      #pragma unroll
      for (int j = 0; j < 4; ++j)
        #pragma unroll
        for (int r = 0; r < 4; ++r)
          acc[i][j][r] = acc[i][j][r] * sigmoidf_(acc[i][j][r]);
  }
  float* C = (mode == 0) ? Cq : ((z == 0) ? Cq : (z == 1) ? Ck : (z == 2) ? Cv : Cg);
  #pragma unroll
  for (int i = 0; i < 4; ++i) {
    const int row = m0 + wm + i * 16 + qd * 4;
    #pragma unroll
    for (int j = 0; j < 4; ++j) {
      const int col = n0 + wn + j * 16 + l15;
      #pragma unroll
      for (int r = 0; r < 4; ++r)
        C[(size_t)(row + r) * GN + col] = acc[i][j][r];
    }
  }
}

// ================= chunked scan: 8x8 tile/lane, LDS-staged tiles of 32 tokens =================
// wave = (b,h,chunk); 4 waves/block = 4 chunks of one (b,h)? No: block = (b,h,chunk-quad)? Grid 256 blocks,
// block g handles (bh = g>>2, chunk-quad = g&3): wave w owns chunk (g&3)*4 + ... NO — keep R4: block owns
// 4 consecutive chunks? Staging is per-chunk-tile; waves must share the tile. So: block = (bh, c) pair where
// all 4 waves work the SAME chunk? That wastes 4x. Instead: block = bh, 4 waves = 4 chunks, and we stage
// 4 chunk-tiles... too much LDS. Compromise: block = (bh, cpair): 2 waves per chunk is wrong for 8x8.
// Final: grid 1024 blocks of 64 threads? No — use 256-thread blocks, 4 waves = 4 DIFFERENT chunks of the
// same (b,h); stage per-wave tiles: 4 chunks x 32 tokens x (k,q,v) — but tiles differ per wave. LDS budget:
// 4 waves x 24KB x2buf = 193KB too big. So tile T=16: 4w x 12.25KB x 2 = 98KB -> fits. k/q/v row for chunk c
// tile = tokens c*128 + tile*16 .. +16.
struct ScanLds1 { float kb[2][4][16 * 64]; float vb[2][4][16 * 64]; float ab[2][4][32]; };
struct ScanLds2 { float kb[2][4][16 * 64]; float qb[2][4][16 * 64]; float vb[2][4][16 * 64]; float ab[2][4][32]; };

// pass 1: compose affine maps over the chunk (Pr/Qr per 8x8 tile)
__global__ __launch_bounds__(256) void scan_p1(const float* __restrict__ k, const float* __restrict__ v,
    const float* __restrict__ al, const float* __restrict__ be,
    float* __restrict__ P, float* __restrict__ Q) {
  __shared__ ScanLds1 L;
  const int tid = threadIdx.x, wv = tid >> 6, lane = tid & 63;
  const int bh = blockIdx.x >> 2;            // 0..63
  const int c = (blockIdx.x & 3) * 4 + wv;   // each wave: its own chunk
  const int b = bh >> 4, h = bh & 15;
  const int r8 = (lane >> 3) * 8, c8 = (lane & 7) * 8;
  const size_t base0 = ((size_t)(b * Sq + c * LCH)) * 1024 + h * 64;   // float index
  const size_t ab0   = ((size_t)(b * Sq + c * LCH)) * 16 + h;
  const int tokw = lane >> 4, seg = lane & 15;   // staging: 4 tokens x 16 segs of 16B
  // stage tile (16 tokens) for THIS wave's chunk into L.*[bi][wv]
  auto stage = [&](int tile, int bi) {
    const size_t tb = base0 + (size_t)tile * 16 * 1024;
    #pragma unroll
    for (int i = 0; i < 4; ++i) {   // 4 groups of 4 tokens
      async16(k + tb + (size_t)(i * 4 + tokw) * 1024 + seg * 4, &L.kb[bi][wv][i * 256]);
      async16(v + tb + (size_t)(i * 4 + tokw) * 1024 + seg * 4, &L.vb[bi][wv][i * 256]);
    }
    if (lane < 32) {
      const float* src = (lane < 16) ? al : be;
      const int tt = lane & 15;
      L.ab[bi][wv][(lane < 16 ? 0 : 16) + tt] = src[ab0 + (size_t)(tile * 16 + tt) * 16];
    }
  };
  float Pr[64], Qr[64];
  #pragma unroll
  for (int i = 0; i < 64; ++i) { Pr[i] = 1.f; Qr[i] = 0.f; }
  stage(0, 0);
  for (int tile = 0; tile < 8; ++tile) {
    __syncthreads();
    if (tile < 7) stage(tile + 1, (tile + 1) & 1);
    const int bi = tile & 1;
    const float* kbp = L.kb[bi][wv];
    const float* vbp = L.vb[bi][wv];
    const float* abp = L.ab[bi][wv];
    #pragma unroll 2
    for (int tt = 0; tt < 16; ++tt) {
      const float a = abp[tt], bt = abp[16 + tt];
      float4 kcv0 = *(const float4*)(kbp + tt * 64 + c8);
      float4 kcv1 = *(const float4*)(kbp + tt * 64 + c8 + 4);
      float4 krv0 = *(const float4*)(kbp + tt * 64 + r8);
      float4 krv1 = *(const float4*)(kbp + tt * 64 + r8 + 4);
      float4 vrv0 = *(const float4*)(vbp + tt * 64 + r8);
      float4 vrv1 = *(const float4*)(vbp + tt * 64 + r8 + 4);
      const float kcv[8] = {kcv0.x, kcv0.y, kcv0.z, kcv0.w, kcv1.x, kcv1.y, kcv1.z, kcv1.w};
      const float krv[8] = {krv0.x, krv0.y, krv0.z, krv0.w, krv1.x, krv1.y, krv1.z, krv1.w};
      const float vrv[8] = {vrv0.x, vrv0.y, vrv0.z, vrv0.w, vrv1.x, vrv1.y, vrv1.z, vrv1.w};
      const float abt = a * bt;
      float c1[8], c2[8];
      #pragma unroll
      for (int i = 0; i < 8; ++i) { c1[i] = abt * krv[i]; c2[i] = bt * vrv[i]; }
      #pragma unroll
      for (int i = 0; i < 8; ++i)
        #pragma unroll
        for (int j = 0; j < 8; ++j) {
          const int e = i * 8 + j;
          const float A = fmaf(-c1[i], kcv[j], a);
          Qr[e] = fmaf(A, Qr[e], c2[i] * kcv[j]);
          Pr[e] *= A;
        }
    }
  }
  const size_t pbase = ((size_t)bh * CCH + c) * 4096 + (size_t)c8;
  #pragma unroll
  for (int i = 0; i < 8; ++i) {
    const size_t pi = pbase + (size_t)(r8 + i) * 64;
    *(float4*)(P + pi)     = make_float4(Pr[i*8],   Pr[i*8+1], Pr[i*8+2], Pr[i*8+3]);
    *(float4*)(P + pi + 4) = make_float4(Pr[i*8+4], Pr[i*8+5], Pr[i*8+6], Pr[i*8+7]);
    *(float4*)(Q + pi)     = make_float4(Qr[i*8],   Qr[i*8+1], Qr[i*8+2], Qr[i*8+3]);
    *(float4*)(Q + pi + 4) = make_float4(Qr[i*8+4], Qr[i*8+5], Qr[i*8+6], Qr[i*8+7]);
  }
}

// pass 2: sequential combine over chunks; writes chunk-initial state over P
__global__ __launch_bounds__(256) void scan_comb(float* __restrict__ P, const float* __restrict__ Q) {
  const int g = blockIdx.x * 256 + threadIdx.x;  // 0..262143
  const int elem = g & 4095;
  const int bh = g >> 12;
  float s = 0.f;
  for (int c = 0; c < CCH; ++c) {
    const size_t idx = ((size_t)bh * CCH + c) * 4096 + elem;
    const float p = P[idx], qq = Q[idx];
    P[idx] = s;
    s = fmaf(p, s, qq);
  }
}

// pass 3: re-iterate chunk from s_init, emit outputs
__global__ __launch_bounds__(256) void scan_p2(const float* __restrict__ q, const float* __restrict__ k,
    const float* __restrict__ v, const float* __restrict__ al, const float* __restrict__ be,
    const float* __restrict__ Pini, float* __restrict__ o) {
  __shared__ ScanLds2 L;
  const int tid = threadIdx.x, wv = tid >> 6, lane = tid & 63;
  const int bh = blockIdx.x >> 2;
  const int c = (blockIdx.x & 3) * 4 + wv;
  const int b = bh >> 4, h = bh & 15;
  const int cb = lane & 7;
  const int r8 = (lane >> 3) * 8, c8 = cb * 8;
  const size_t base0 = ((size_t)(b * Sq + c * LCH)) * 1024 + h * 64;
  const size_t ab0   = ((size_t)(b * Sq + c * LCH)) * 16 + h;
  const size_t pbase = ((size_t)bh * CCH + c) * 4096 + (size_t)c8;
  const int tokw = lane >> 4, seg = lane & 15;
  auto stage = [&](int tile, int bi) {
    const size_t tb = base0 + (size_t)tile * 16 * 1024;
    #pragma unroll
    for (int i = 0; i < 4; ++i) {
      async16(k + tb + (size_t)(i * 4 + tokw) * 1024 + seg * 4, &L.kb[bi][wv][i * 256]);
      async16(q + tb + (size_t)(i * 4 + tokw) * 1024 + seg * 4, &L.qb[bi][wv][i * 256]);
      async16(v + tb + (size_t)(i * 4 + tokw) * 1024 + seg * 4, &L.vb[bi][wv][i * 256]);
    }
    if (lane < 32) {
      const float* src = (lane < 16) ? al : be;
      const int tt = lane & 15;
      L.ab[bi][wv][(lane < 16 ? 0 : 16) + tt] = src[ab0 + (size_t)(tile * 16 + tt) * 16];
    }
  };
  float st[64];
  #pragma unroll
  for (int i = 0; i < 8; ++i) {
    float4 s0 = *(const float4*)(Pini + pbase + (size_t)(r8 + i) * 64);
    float4 s1 = *(const float4*)(Pini + pbase + (size_t)(r8 + i) * 64 + 4);
    st[i*8]   = s0.x; st[i*8+1] = s0.y; st[i*8+2] = s0.z; st[i*8+3] = s0.w;
    st[i*8+4] = s1.x; st[i*8+5] = s1.y; st[i*8+6] = s1.z; st[i*8+7] = s1.w;
  }
  stage(0, 0);
  const bool hi4 = (cb & 4), hi2 = (cb & 2), hi1 = (cb & 1);
  for (int tile = 0; tile < 8; ++tile) {
    __syncthreads();
    if (tile < 7) stage(tile + 1, (tile + 1) & 1);
    const int bi = tile & 1;
    const float* kbp = L.kb[bi][wv];
    const float* qbp = L.qb[bi][wv];
    const float* vbp = L.vb[bi][wv];
    const float* abp = L.ab[bi][wv];
    #pragma unroll 2
    for (int tt = 0; tt < 16; ++tt) {
      const int t = tile * 16 + tt;
      const float a = abp[tt], bt = abp[16 + tt];
      float4 kcv0 = *(const float4*)(kbp + tt * 64 + c8);
      float4 kcv1 = *(const float4*)(kbp + tt * 64 + c8 + 4);
      float4 qcv0 = *(const float4*)(qbp + tt * 64 + c8);
      float4 qcv1 = *(const float4*)(qbp + tt * 64 + c8 + 4);
      float4 krv0 = *(const float4*)(kbp + tt * 64 + r8);
      float4 krv1 = *(const float4*)(kbp + tt * 64 + r8 + 4);
      float4 vrv0 = *(const float4*)(vbp + tt * 64 + r8);
      float4 vrv1 = *(const float4*)(vbp + tt * 64 + r8 + 4);
      const float kcv[8] = {kcv0.x, kcv0.y, kcv0.z, kcv0.w, kcv1.x, kcv1.y, kcv1.z, kcv1.w};
      const float qcv[8] = {qcv0.x, qcv0.y, qcv0.z, qcv0.w, qcv1.x, qcv1.y, qcv1.z, qcv1.w};
      const float krv[8] = {krv0.x, krv0.y, krv0.z, krv0.w, krv1.x, krv1.y, krv1.z, krv1.w};
      const float vrv[8] = {vrv0.x, vrv0.y, vrv0.z, vrv0.w, vrv1.x, vrv1.y, vrv1.z, vrv1.w};
      const float abt = a * bt;
      float c1[8], c2[8];
      #pragma unroll
      for (int i = 0; i < 8; ++i) { c1[i] = abt * krv[i]; c2[i] = bt * vrv[i]; }
      float p[8];
      #pragma unroll
      for (int i = 0; i < 8; ++i) p[i] = 0.f;
      #pragma unroll
      for (int i = 0; i < 8; ++i)
        #pragma unroll
        for (int j = 0; j < 8; ++j) {
          const int e = i * 8 + j;
          const float A = fmaf(-c1[i], kcv[j], a);
          st[e] = fmaf(A, st[e], c2[i] * kcv[j]);
          p[i] = fmaf(st[e], qcv[j], p[i]);
        }
      // reduce-scatter across the 8 col-lanes (R4-verified): lane ends with one full row sum
      float r4[4];
      #pragma unroll
      for (int i = 0; i < 4; ++i) {
        const float send = hi4 ? p[i] : p[i + 4];
        const float recv = __shfl_xor(send, 4);
        r4[i] = (hi4 ? p[i + 4] : p[i]) + recv;
      }
      float r2[2];
      #pragma unroll
      for (int i = 0; i < 2; ++i) {
        const float send = hi2 ? r4[i] : r4[i + 2];
        const float recv = __shfl_xor(send, 2);
        r2[i] = (hi2 ? r4[i + 2] : r4[i]) + recv;
      }
      {
        const float send = hi1 ? r2[0] : r2[1];
        const float recv = __shfl_xor(send, 1);
        const float tot = (hi1 ? r2[1] : r2[0]) + recv;
        o[base0 + (size_t)t * 1024 + lane] = tot;
      }
    }
  }
}

// ---------------- LayerNorm + silu-gate, write bf16 ----------------
__global__ __launch_bounds__(256) void ln_gate_kernel(const float* __restrict__ o, const float* __restrict__ g,
    const float* __restrict__ ln_g, const float* __restrict__ ln_b, u16* __restrict__ y) {
  const int t = blockIdx.x, tid = threadIdx.x;
  const size_t row = (size_t)t * 1024;
  float4 xv = *(const float4*)(o + row + tid * 4);
  float s  = xv.x + xv.y + xv.z + xv.w;
  float s2 = xv.x * xv.x + xv.y * xv.y + xv.z * xv.z + xv.w * xv.w;
  #pragma unroll
  for (int m = 1; m < 64; m <<= 1) { s += __shfl_xor(s, m); s2 += __shfl_xor(s2, m); }
  __shared__ float red[8];
  const int w = tid >> 6, lane = tid & 63;
  if (lane == 0) { red[w] = s; red[4 + w] = s2; }
  __syncthreads();
  s  = red[0] + red[1] + red[2] + red[3];
  s2 = red[4] + red[5] + red[6] + red[7];
  const float mu = s * (1.f / 1024.f);
  const float var = s2 * (1.f / 1024.f) - mu * mu;
  const float rstd = rsqrtf(var + 1e-5f);
  float4 gv = *(const float4*)(g + row + tid * 4);
  float4 lg = *(const float4*)(ln_g + tid * 4);
  float4 lb = *(const float4*)(ln_b + tid * 4);
  ushort4 u;
  u.x = f2bf(((xv.x - mu) * rstd * lg.x + lb.x) * (gv.x * sigmoidf_(gv.x)));
  u.y = f2bf(((xv.y - mu) * rstd * lg.y + lb.y) * (gv.y * sigmoidf_(gv.y)));
  u.z = f2bf(((xv.z - mu) * rstd * lg.z + lb.z) * (gv.z * sigmoidf_(gv.z)));
  u.w = f2bf(((xv.w - mu) * rstd * lg.w + lb.w) * (gv.w * sigmoidf_(gv.w)));
  *(ushort4*)(y + row + tid * 4) = u;
}

extern "C" void kernel_launch(void* const* d_in, const int* in_sizes, int n_in,
                              void* d_out, int out_size, void* d_ws, size_t ws_size,
                              hipStream_t stream) {
  const float* x    = (const float*)d_in[0];
  const float* Wq   = (const float*)d_in[1];
  const float* Wk   = (const float*)d_in[2];
  const float* Wv   = (const float*)d_in[3];
  const float* Wa   = (const float*)d_in[4];
  const float* ba   = (const float*)d_in[5];
  const float* Wb   = (const float*)d_in[6];
  const float* bb   = (const float*)d_in[7];
  const float* Wg   = (const float*)d_in[8];
  const float* Wo   = (const float*)d_in[9];
  const float* ln_g = (const float*)d_in[10];
  const float* ln_b = (const float*)d_in[11];
  float* out = (float*)d_out;
  char* ws = (char*)d_ws;

  u16*   wb  = (u16*)(ws + OFF_WB);
  u16*   xb  = (u16*)(ws + OFF_XB);   // x-bf16 -> Qc -> y-bf16
  float* qf  = (float*)(ws + OFF_Q);
  float* kf  = (float*)(ws + OFF_K);
  float* vf  = (float*)(ws + OFF_V);
  float* gf  = (float*)(ws + OFF_G);
  float* al  = (float*)(ws + OFF_AL);
  float* be  = (float*)(ws + OFF_BE);
  u16*   wab = (u16*)(ws + OFF_P);    // Wab bf16 during GEMM; region later becomes P
  float* Pb  = (float*)(ws + OFF_P);
  float* Qc  = (float*)(ws + OFF_XB); // reuses dead x-bf16 region
  float* of  = (float*)(ws + OFF_O);
  u16*   yb  = xb;

  cvt_x_kernel<<<8192, 256, 0, stream>>>(x, xb);
  cvt_w_kernel<<<dim3(1024, 1, 5), 256, 0, stream>>>(Wq, Wk, Wv, Wg, Wo, wb);
  cvt_ab_kernel<<<128, 256, 0, stream>>>(Wa, Wb, wab);
  // projections q,k,v,g + alpha/beta, with fused l2norm/silu/sigmoid epilogues
  gemm_bt<<<dim3(64, 8, 5), 256, 0, stream>>>(xb, wb, wab, qf, kf, vf, gf, al, be, ba, bb, 1);
  // chunked scan (8x8 tile per lane, LDS-staged 16-token tiles, double-buffered)
  scan_p1<<<256, 256, 0, stream>>>(kf, vf, al, be, Pb, Qc);
  scan_comb<<<1024, 256, 0, stream>>>(Pb, Qc);
  scan_p2<<<256, 256, 0, stream>>>(qf, kf, vf, al, be, Pb, of);
  // epilogue
  ln_gate_kernel<<<8192, 256, 0, stream>>>(of, gf, ln_g, ln_b, yb);
  gemm_bt<<<dim3(64, 8, 1), 256, 0, stream>>>(yb, wb + (size_t)4 * 1024 * 1024, wab,
                                              out, out, out, out, al, be, ba, bb, 0);
}

// Round 7
// 447.756 us; speedup vs baseline: 1.1031x; 1.0152x over previous
//
#include <hip/hip_runtime.h>

typedef unsigned short u16;
typedef __bf16 bf16x8 __attribute__((ext_vector_type(8)));
typedef float f32x4 __attribute__((ext_vector_type(4)));

constexpr int Bq  = 4;
constexpr int Sq  = 2048;
constexpr int Hq  = 1024;
constexpr int NHq = 16;
constexpr int HDq = 64;
constexpr int CCH = 16;    // chunks
constexpr int LCH = 128;   // chunk length

// workspace layout (bytes), total 212,860,928
constexpr size_t OFF_WB = 0;             // W bf16: 5*1M*2 = 10,485,760
constexpr size_t OFF_XB = 10485760;      // 16,777,216: x-bf16 -> Qc (scan) -> y-bf16 (epilogue)
constexpr size_t OFF_Q  = 27262976;      // q fp32: 33,554,432
constexpr size_t OFF_K  = 60817408;
constexpr size_t OFF_V  = 94371840;
constexpr size_t OFF_G  = 127926272;
constexpr size_t OFF_AL = 161480704;     // alpha: 524,288
constexpr size_t OFF_BE = 162004992;
constexpr size_t OFF_P  = 162529280;     // Wab bf16 (256 KB) during GEMM -> chunk P (16 MB) during scan
constexpr size_t OFF_O  = 179306496;     // of fp32: 33,554,432 (end 212,860,928)

__device__ __forceinline__ u16 f2bf(float f) {
  unsigned u = __float_as_uint(f);
  u += 0x7fffu + ((u >> 16) & 1u);
  return (u16)(u >> 16);
}
__device__ __forceinline__ float sigmoidf_(float x) { return 1.f / (1.f + __expf(-x)); }

__device__ __forceinline__ void async16(const void* g, void* l) {
  __builtin_amdgcn_global_load_lds((const __attribute__((address_space(1))) void*)g,
                                   (__attribute__((address_space(3))) void*)l, 16, 0, 0);
}

// ---------------- converts ----------------
__global__ __launch_bounds__(256) void cvt_x_kernel(const float* __restrict__ in, u16* __restrict__ outp) {
  const size_t i = ((size_t)blockIdx.x * 256 + threadIdx.x) * 4;
  float4 f = *(const float4*)(in + i);
  ushort4 u; u.x = f2bf(f.x); u.y = f2bf(f.y); u.z = f2bf(f.z); u.w = f2bf(f.w);
  *(ushort4*)(outp + i) = u;
}

__global__ __launch_bounds__(256) void cvt_w_kernel(const float* __restrict__ w0, const float* __restrict__ w1,
    const float* __restrict__ w2, const float* __restrict__ w3, const float* __restrict__ w4,
    u16* __restrict__ outp) {
  const int z = blockIdx.z;
  const float* src = (z == 0) ? w0 : (z == 1) ? w1 : (z == 2) ? w2 : (z == 3) ? w3 : w4;
  const size_t i = ((size_t)blockIdx.x * 256 + threadIdx.x) * 4;
  float4 f = *(const float4*)(src + i);
  ushort4 u; u.x = f2bf(f.x); u.y = f2bf(f.y); u.z = f2bf(f.z); u.w = f2bf(f.w);
  *(ushort4*)(outp + (size_t)z * (1024 * 1024) + i) = u;
}

// Wab: 128x1024 bf16; rows 0..15 = Wa, 16..31 = Wb, rest zero
__global__ __launch_bounds__(256) void cvt_ab_kernel(const float* __restrict__ Wa, const float* __restrict__ Wb,
    u16* __restrict__ outp) {
  const size_t i = ((size_t)blockIdx.x * 256 + threadIdx.x) * 4;
  const int row = (int)(i >> 10);
  ushort4 u;
  if (row < 32) {
    const float* src = (row < 16) ? (Wa + i) : (Wb + i - 16 * 1024);
    float4 f = *(const float4*)src;
    u.x = f2bf(f.x); u.y = f2bf(f.y); u.z = f2bf(f.z); u.w = f2bf(f.w);
  } else {
    u.x = u.y = u.z = u.w = 0;
  }
  *(ushort4*)(outp + i) = u;
}

// ---------------- bf16 MFMA GEMM (m97 structure) with fused epilogues ----------------
// mode 0: plain store to Cq.
// mode 1: z=0 q(l2norm), z=1 k(l2norm), z=2 v(silu), z=3 g(plain), z=4 alpha/beta(sigmoid+bias, y==0 only)
__global__ __launch_bounds__(256) void gemm_bt(const u16* __restrict__ A, const u16* __restrict__ Wall,
    const u16* __restrict__ Wab,
    float* __restrict__ Cq, float* __restrict__ Ck, float* __restrict__ Cv, float* __restrict__ Cg,
    float* __restrict__ al, float* __restrict__ be,
    const float* __restrict__ ba, const float* __restrict__ bb, int mode) {
  constexpr int GK = 1024, GN = 1024;
  const int z = blockIdx.z;
  if (mode == 1 && z == 4 && blockIdx.y > 0) return;
  __shared__ __align__(16) u16 As[128 * 32];
  __shared__ __align__(16) u16 Bs[128 * 32];
  const int tid = threadIdx.x;
  const int w = tid >> 6, lane = tid & 63;
  const int m0 = blockIdx.x * 128, n0 = blockIdx.y * 128;
  const u16* W = (mode == 1 && z == 4) ? Wab : (Wall + (size_t)z * (1024 * 1024));
  const int rrow = lane >> 2;
  const int kc8 = (lane & 3) * 8;
  const u16* gA = A + (size_t)(m0 + w * 32 + rrow) * GK + kc8;
  const u16* gB = W + (size_t)(n0 + w * 32 + rrow) * GK + kc8;
  u16* lA = As + (w * 32) * 32;
  u16* lB = Bs + (w * 32) * 32;
  const int qd = lane >> 4, l15 = lane & 15;
  const int wm = (w >> 1) * 64, wn = (w & 1) * 64;
  f32x4 acc[4][4] = {};
  for (int kt = 0; kt < GK; kt += 32) {
    async16(gA,           lA);
    async16(gA + 16 * GK, lA + 16 * 32);
    async16(gB,           lB);
    async16(gB + 16 * GK, lB + 16 * 32);
    gA += 32; gB += 32;
    __syncthreads();
    bf16x8 af[4], bfr[4];
    #pragma unroll
    for (int i = 0; i < 4; ++i) {
      af[i]  = *(const bf16x8*)(As + (wm + i * 16 + l15) * 32 + qd * 8);
      bfr[i] = *(const bf16x8*)(Bs + (wn + i * 16 + l15) * 32 + qd * 8);
    }
    #pragma unroll
    for (int i = 0; i < 4; ++i)
      #pragma unroll
      for (int j = 0; j < 4; ++j)
        acc[i][j] = __builtin_amdgcn_mfma_f32_16x16x32_bf16(af[i], bfr[j], acc[i][j], 0, 0, 0);
    __syncthreads();
  }
  // ---- epilogues ---- C/D layout: col = l15, row = qd*4 + reg
  if (mode == 1 && z == 4) {
    if (wn == 0) {
      const float bav = ba[l15], bbv = bb[l15];
      #pragma unroll
      for (int i = 0; i < 4; ++i) {
        const int row = m0 + wm + i * 16 + qd * 4;
        #pragma unroll
        for (int r = 0; r < 4; ++r) {
          al[(size_t)(row + r) * 16 + l15] = sigmoidf_(acc[i][0][r] + bav);
          be[(size_t)(row + r) * 16 + l15] = sigmoidf_(acc[i][1][r] + bbv);
        }
      }
    }
    return;
  }
  if (mode == 1 && (z == 0 || z == 1)) {
    #pragma unroll
    for (int i = 0; i < 4; ++i)
      #pragma unroll
      for (int r = 0; r < 4; ++r) {
        float ss = acc[i][0][r] * acc[i][0][r] + acc[i][1][r] * acc[i][1][r]
                 + acc[i][2][r] * acc[i][2][r] + acc[i][3][r] * acc[i][3][r];
        ss += __shfl_xor(ss, 1); ss += __shfl_xor(ss, 2);
        ss += __shfl_xor(ss, 4); ss += __shfl_xor(ss, 8);
        const float rn = 1.f / fmaxf(sqrtf(ss), 1e-12f);
        acc[i][0][r] *= rn; acc[i][1][r] *= rn; acc[i][2][r] *= rn; acc[i][3][r] *= rn;
      }
  } else if (mode == 1 && z == 2) {
    #pragma unroll
    for (int i = 0; i < 4; ++i)
      #pragma unroll
      for (int j = 0; j < 4; ++j)
        #pragma unroll
        for (int r = 0; r < 4; ++r)
          acc[i][j][r] = acc[i][j][r] * sigmoidf_(acc[i][j][r]);
  }
  float* C = (mode == 0) ? Cq : ((z == 0) ? Cq : (z == 1) ? Ck : (z == 2) ? Cv : Cg);
  #pragma unroll
  for (int i = 0; i < 4; ++i) {
    const int row = m0 + wm + i * 16 + qd * 4;
    #pragma unroll
    for (int j = 0; j < 4; ++j) {
      const int col = n0 + wn + j * 16 + l15;
      #pragma unroll
      for (int r = 0; r < 4; ++r)
        C[(size_t)(row + r) * GN + col] = acc[i][j][r];
    }
  }
}

// ================= chunked scan: row-split waves + shared LDS staging =================
// Block = (bh, chunk-pair). 4 waves: wave wv -> chunk cw=wv>>1 of the pair, row-half = wv&1.
// Wave owns 32 rows x 64 cols; lane: rg=lane>>3 (4-row group), cg=lane&7 (8-col group).
// Tiles of 16 tokens staged to LDS (double-buffered) via global_load_lds, shared by the
// 2 waves of each chunk. Grid = 512 blocks -> 2 blocks/CU -> 2 waves/SIMD.
struct ScanLds1 { float kb[2][2][16 * 64]; float vb[2][2][16 * 64]; float ab[2][2][32]; };
struct ScanLds2 { float kb[2][2][16 * 64]; float qb[2][2][16 * 64]; float vb[2][2][16 * 64]; float ab[2][2][32]; };

// pass 1: compose affine maps over the chunk (Pr/Qr, 4x8 tile per lane)
__global__ __launch_bounds__(256, 2) void scan_p1(const float* __restrict__ k, const float* __restrict__ v,
    const float* __restrict__ al, const float* __restrict__ be,
    float* __restrict__ P, float* __restrict__ Q) {
  __shared__ ScanLds1 L;
  const int tid = threadIdx.x, wv = tid >> 6, lane = tid & 63;
  const int bh = blockIdx.x >> 3, cp = blockIdx.x & 7;
  const int b = bh >> 4, h = bh & 15;
  const int cw = wv >> 1, half = wv & 1;
  const int c = cp * 2 + cw;
  const int rg = lane >> 3, cg = lane & 7;
  const int r0 = half * 32 + rg * 4, c8 = cg * 8;
  const size_t base0[2] = { ((size_t)(b * Sq + (cp * 2 + 0) * LCH)) * 1024 + h * 64,
                            ((size_t)(b * Sq + (cp * 2 + 1) * LCH)) * 1024 + h * 64 };
  const size_t ab0[2]   = { ((size_t)(b * Sq + (cp * 2 + 0) * LCH)) * 16 + h,
                            ((size_t)(b * Sq + (cp * 2 + 1) * LCH)) * 16 + h };
  const int tokw = lane >> 4, seg = lane & 15;
  auto stage = [&](int tile, int bi) {
    #pragma unroll
    for (int j = 0; j < 4; ++j) {        // 16 jobs: (chunk, arr{k,v}, quarter)
      const int job = wv * 4 + j;
      const int ch = job >> 3, rem = job & 7, arr = rem >> 2, i = rem & 3;
      const float* src = arr ? v : k;
      float* dst = arr ? &L.vb[bi][ch][i * 256] : &L.kb[bi][ch][i * 256];
      async16(src + base0[ch] + (size_t)(tile * 16 + i * 4 + tokw) * 1024 + seg * 4, dst);
    }
    if (wv == 0) {                        // a/b: 64 values, one lane each
      const int ch = lane >> 5, w16 = (lane >> 4) & 1, tt = lane & 15;
      const float* s = w16 ? be : al;
      L.ab[bi][ch][w16 * 16 + tt] = s[ab0[ch] + (size_t)(tile * 16 + tt) * 16];
    }
  };
  float Pr[32], Qr[32];
  #pragma unroll
  for (int i = 0; i < 32; ++i) { Pr[i] = 1.f; Qr[i] = 0.f; }
  stage(0, 0);
  for (int tile = 0; tile < 8; ++tile) {
    __syncthreads();
    if (tile < 7) stage(tile + 1, (tile + 1) & 1);
    const int bi = tile & 1;
    const float* kbp = L.kb[bi][cw];
    const float* vbp = L.vb[bi][cw];
    const float* abp = L.ab[bi][cw];
    #pragma unroll 2
    for (int tt = 0; tt < 16; ++tt) {
      const float a = abp[tt], bt = abp[16 + tt];
      float4 kcv0 = *(const float4*)(kbp + tt * 64 + c8);
      float4 kcv1 = *(const float4*)(kbp + tt * 64 + c8 + 4);
      float4 krvv = *(const float4*)(kbp + tt * 64 + r0);
      float4 vrvv = *(const float4*)(vbp + tt * 64 + r0);
      const float kcv[8] = {kcv0.x, kcv0.y, kcv0.z, kcv0.w, kcv1.x, kcv1.y, kcv1.z, kcv1.w};
      const float krv[4] = {krvv.x, krvv.y, krvv.z, krvv.w};
      const float vrv[4] = {vrvv.x, vrvv.y, vrvv.z, vrvv.w};
      const float abt = a * bt;
      float c1[4], c2[4];
      #pragma unroll
      for (int i = 0; i < 4; ++i) { c1[i] = abt * krv[i]; c2[i] = bt * vrv[i]; }
      #pragma unroll
      for (int i = 0; i < 4; ++i)
        #pragma unroll
        for (int j = 0; j < 8; ++j) {
          const int e = i * 8 + j;
          const float A = fmaf(-c1[i], kcv[j], a);
          Qr[e] = fmaf(A, Qr[e], c2[i] * kcv[j]);
          Pr[e] *= A;
        }
    }
  }
  const size_t pbase = ((size_t)bh * CCH + c) * 4096 + (size_t)c8;
  #pragma unroll
  for (int i = 0; i < 4; ++i) {
    const size_t pi = pbase + (size_t)(r0 + i) * 64;
    *(float4*)(P + pi) = make_float4(Pr[i*8],   Pr[i*8+1], Pr[i*8+2], Pr[i*8+3]);
    *(float4*)(P + pi + 4) = make_float4(Pr[i*8+4], Pr[i*8+5], Pr[i*8+6], Pr[i*8+7]);
    *(float4*)(Q + pi) = make_float4(Qr[i*8],   Qr[i*8+1], Qr[i*8+2], Qr[i*8+3]);
    *(float4*)(Q + pi + 4) = make_float4(Qr[i*8+4], Qr[i*8+5], Qr[i*8+6], Qr[i*8+7]);
  }
}

// pass 2: sequential combine over chunks; writes chunk-initial state over P
__global__ __launch_bounds__(256) void scan_comb(float* __restrict__ P, const float* __restrict__ Q) {
  const int g = blockIdx.x * 256 + threadIdx.x;  // 0..262143
  const int elem = g & 4095;
  const int bh = g >> 12;
  float s = 0.f;
  for (int c = 0; c < CCH; ++c) {
    const size_t idx = ((size_t)bh * CCH + c) * 4096 + elem;
    const float p = P[idx], qq = Q[idx];
    P[idx] = s;
    s = fmaf(p, s, qq);
  }
}

// pass 3: re-iterate chunk from s_init, emit outputs
__global__ __launch_bounds__(256, 2) void scan_p2(const float* __restrict__ q, const float* __restrict__ k,
    const float* __restrict__ v, const float* __restrict__ al, const float* __restrict__ be,
    const float* __restrict__ Pini, float* __restrict__ o) {
  __shared__ ScanLds2 L;
  const int tid = threadIdx.x, wv = tid >> 6, lane = tid & 63;
  const int bh = blockIdx.x >> 3, cp = blockIdx.x & 7;
  const int b = bh >> 4, h = bh & 15;
  const int cw = wv >> 1, half = wv & 1;
  const int c = cp * 2 + cw;
  const int rg = lane >> 3, cg = lane & 7;
  const int r0 = half * 32 + rg * 4, c8 = cg * 8;
  const size_t base0[2] = { ((size_t)(b * Sq + (cp * 2 + 0) * LCH)) * 1024 + h * 64,
                            ((size_t)(b * Sq + (cp * 2 + 1) * LCH)) * 1024 + h * 64 };
  const size_t ab0[2]   = { ((size_t)(b * Sq + (cp * 2 + 0) * LCH)) * 16 + h,
                            ((size_t)(b * Sq + (cp * 2 + 1) * LCH)) * 16 + h };
  const size_t mybase = base0[cw];
  const size_t pbase = ((size_t)bh * CCH + c) * 4096 + (size_t)c8;
  const int tokw = lane >> 4, seg = lane & 15;
  auto stage = [&](int tile, int bi) {
    #pragma unroll
    for (int j = 0; j < 6; ++j) {        // 24 jobs: (chunk, arr{k,q,v}, quarter)
      const int job = wv * 6 + j;
      const int ch = job / 12, rem = job % 12, arr = rem >> 2, i = rem & 3;
      const float* src = (arr == 0) ? k : (arr == 1) ? q : v;
      float* dst = (arr == 0) ? &L.kb[bi][ch][i * 256] : (arr == 1) ? &L.qb[bi][ch][i * 256]
                                                                    : &L.vb[bi][ch][i * 256];
      async16(src + base0[ch] + (size_t)(tile * 16 + i * 4 + tokw) * 1024 + seg * 4, dst);
    }
    if (wv == 0) {
      const int ch = lane >> 5, w16 = (lane >> 4) & 1, tt = lane & 15;
      const float* s = w16 ? be : al;
      L.ab[bi][ch][w16 * 16 + tt] = s[ab0[ch] + (size_t)(tile * 16 + tt) * 16];
    }
  };
  float st[32];
  #pragma unroll
  for (int i = 0; i < 4; ++i) {
    float4 s0 = *(const float4*)(Pini + pbase + (size_t)(r0 + i) * 64);
    float4 s1 = *(const float4*)(Pini + pbase + (size_t)(r0 + i) * 64 + 4);
    st[i*8]   = s0.x; st[i*8+1] = s0.y; st[i*8+2] = s0.z; st[i*8+3] = s0.w;
    st[i*8+4] = s1.x; st[i*8+5] = s1.y; st[i*8+6] = s1.z; st[i*8+7] = s1.w;
  }
  stage(0, 0);
  const bool hi4 = (cg & 4), hi2 = (cg & 2);
  const int rowIdx = r0 + (cg >> 1);
  const bool doStore = ((cg & 1) == 0);
  for (int tile = 0; tile < 8; ++tile) {
    __syncthreads();
    if (tile < 7) stage(tile + 1, (tile + 1) & 1);
    const int bi = tile & 1;
    const float* kbp = L.kb[bi][cw];
    const float* qbp = L.qb[bi][cw];
    const float* vbp = L.vb[bi][cw];
    const float* abp = L.ab[bi][cw];
    #pragma unroll 2
    for (int tt = 0; tt < 16; ++tt) {
      const int t = tile * 16 + tt;
      const float a = abp[tt], bt = abp[16 + tt];
      float4 kcv0 = *(const float4*)(kbp + tt * 64 + c8);
      float4 kcv1 = *(const float4*)(kbp + tt * 64 + c8 + 4);
      float4 qcv0 = *(const float4*)(qbp + tt * 64 + c8);
      float4 qcv1 = *(const float4*)(qbp + tt * 64 + c8 + 4);
      float4 krvv = *(const float4*)(kbp + tt * 64 + r0);
      float4 vrvv = *(const float4*)(vbp + tt * 64 + r0);
      const float kcv[8] = {kcv0.x, kcv0.y, kcv0.z, kcv0.w, kcv1.x, kcv1.y, kcv1.z, kcv1.w};
      const float qcv[8] = {qcv0.x, qcv0.y, qcv0.z, qcv0.w, qcv1.x, qcv1.y, qcv1.z, qcv1.w};
      const float krv[4] = {krvv.x, krvv.y, krvv.z, krvv.w};
      const float vrv[4] = {vrvv.x, vrvv.y, vrvv.z, vrvv.w};
      const float abt = a * bt;
      float c1[4], c2[4];
      #pragma unroll
      for (int i = 0; i < 4; ++i) { c1[i] = abt * krv[i]; c2[i] = bt * vrv[i]; }
      float p[4];
      #pragma unroll
      for (int i = 0; i < 4; ++i) p[i] = 0.f;
      #pragma unroll
      for (int i = 0; i < 4; ++i)
        #pragma unroll
        for (int j = 0; j < 8; ++j) {
          const int e = i * 8 + j;
          const float A = fmaf(-c1[i], kcv[j], a);
          st[e] = fmaf(A, st[e], c2[i] * kcv[j]);
          p[i] = fmaf(st[e], qcv[j], p[i]);
        }
      // reduce-scatter over the 8 col-lanes (R5-verified): lane (rg,cg) -> row r0+(cg>>1), even cg stores
      float r2[2];
      #pragma unroll
      for (int i = 0; i < 2; ++i) {
        const float send = hi4 ? p[i] : p[i + 2];
        const float recv = __shfl_xor(send, 4);
        r2[i] = (hi4 ? p[i + 2] : p[i]) + recv;
      }
      float r1;
      {
        const float send = hi2 ? r2[0] : r2[1];
        const float recv = __shfl_xor(send, 2);
        r1 = (hi2 ? r2[1] : r2[0]) + recv;
      }
      const float tot = r1 + __shfl_xor(r1, 1);
      if (doStore) o[mybase + (size_t)t * 1024 + rowIdx] = tot;
    }
  }
}

// ---------------- LayerNorm + silu-gate, write bf16 ----------------
__global__ __launch_bounds__(256) void ln_gate_kernel(const float* __restrict__ o, const float* __restrict__ g,
    const float* __restrict__ ln_g, const float* __restrict__ ln_b, u16* __restrict__ y) {
  const int t = blockIdx.x, tid = threadIdx.x;
  const size_t row = (size_t)t * 1024;
  float4 xv = *(const float4*)(o + row + tid * 4);
  float s  = xv.x + xv.y + xv.z + xv.w;
  float s2 = xv.x * xv.x + xv.y * xv.y + xv.z * xv.z + xv.w * xv.w;
  #pragma unroll
  for (int m = 1; m < 64; m <<= 1) { s += __shfl_xor(s, m); s2 += __shfl_xor(s2, m); }
  __shared__ float red[8];
  const int w = tid >> 6, lane = tid & 63;
  if (lane == 0) { red[w] = s; red[4 + w] = s2; }
  __syncthreads();
  s  = red[0] + red[1] + red[2] + red[3];
  s2 = red[4] + red[5] + red[6] + red[7];
  const float mu = s * (1.f / 1024.f);
  const float var = s2 * (1.f / 1024.f) - mu * mu;
  const float rstd = rsqrtf(var + 1e-5f);
  float4 gv = *(const float4*)(g + row + tid * 4);
  float4 lg = *(const float4*)(ln_g + tid * 4);
  float4 lb = *(const float4*)(ln_b + tid * 4);
  ushort4 u;
  u.x = f2bf(((xv.x - mu) * rstd * lg.x + lb.x) * (gv.x * sigmoidf_(gv.x)));
  u.y = f2bf(((xv.y - mu) * rstd * lg.y + lb.y) * (gv.y * sigmoidf_(gv.y)));
  u.z = f2bf(((xv.z - mu) * rstd * lg.z + lb.z) * (gv.z * sigmoidf_(gv.z)));
  u.w = f2bf(((xv.w - mu) * rstd * lg.w + lb.w) * (gv.w * sigmoidf_(gv.w)));
  *(ushort4*)(y + row + tid * 4) = u;
}

extern "C" void kernel_launch(void* const* d_in, const int* in_sizes, int n_in,
                              void* d_out, int out_size, void* d_ws, size_t ws_size,
                              hipStream_t stream) {
  const float* x    = (const float*)d_in[0];
  const float* Wq   = (const float*)d_in[1];
  const float* Wk   = (const float*)d_in[2];
  const float* Wv   = (const float*)d_in[3];
  const float* Wa   = (const float*)d_in[4];
  const float* ba   = (const float*)d_in[5];
  const float* Wb   = (const float*)d_in[6];
  const float* bb   = (const float*)d_in[7];
  const float* Wg   = (const float*)d_in[8];
  const float* Wo   = (const float*)d_in[9];
  const float* ln_g = (const float*)d_in[10];
  const float* ln_b = (const float*)d_in[11];
  float* out = (float*)d_out;
  char* ws = (char*)d_ws;

  u16*   wb  = (u16*)(ws + OFF_WB);
  u16*   xb  = (u16*)(ws + OFF_XB);   // x-bf16 -> Qc -> y-bf16
  float* qf  = (float*)(ws + OFF_Q);
  float* kf  = (float*)(ws + OFF_K);
  float* vf  = (float*)(ws + OFF_V);
  float* gf  = (float*)(ws + OFF_G);
  float* al  = (float*)(ws + OFF_AL);
  float* be  = (float*)(ws + OFF_BE);
  u16*   wab = (u16*)(ws + OFF_P);    // Wab bf16 during GEMM; region later becomes P
  float* Pb  = (float*)(ws + OFF_P);
  float* Qc  = (float*)(ws + OFF_XB); // reuses dead x-bf16 region
  float* of  = (float*)(ws + OFF_O);
  u16*   yb  = xb;

  cvt_x_kernel<<<8192, 256, 0, stream>>>(x, xb);
  cvt_w_kernel<<<dim3(1024, 1, 5), 256, 0, stream>>>(Wq, Wk, Wv, Wg, Wo, wb);
  cvt_ab_kernel<<<128, 256, 0, stream>>>(Wa, Wb, wab);
  // projections q,k,v,g + alpha/beta, with fused l2norm/silu/sigmoid epilogues
  gemm_bt<<<dim3(64, 8, 5), 256, 0, stream>>>(xb, wb, wab, qf, kf, vf, gf, al, be, ba, bb, 1);
  // chunked scan: row-split waves, shared LDS staging, 512 blocks -> 2 blocks/CU
  scan_p1<<<512, 256, 0, stream>>>(kf, vf, al, be, Pb, Qc);
  scan_comb<<<1024, 256, 0, stream>>>(Pb, Qc);
  scan_p2<<<512, 256, 0, stream>>>(qf, kf, vf, al, be, Pb, of);
  // epilogue
  ln_gate_kernel<<<8192, 256, 0, stream>>>(of, gf, ln_g, ln_b, yb);
  gemm_bt<<<dim3(64, 8, 1), 256, 0, stream>>>(yb, wb + (size_t)4 * 1024 * 1024, wab,
                                              out, out, out, out, al, be, ba, bb, 0);
}